// Round 8
// baseline (337.712 us; speedup 1.0000x reference)
//
#include <hip/hip_runtime.h>
#include <math.h>

#define D_MODEL 512
#define N_HEADS 8
#define DK 64
#define QSCALE (0.0625f * 1.44269504089f)

typedef __attribute__((ext_vector_type(8))) short short8;
typedef __attribute__((ext_vector_type(4))) float f32x4;

typedef __attribute__((address_space(1))) const unsigned as1_uint;
typedef __attribute__((address_space(3))) unsigned as3_uint;

__device__ __forceinline__ unsigned short f2bf(float f) {
    unsigned u = __builtin_bit_cast(unsigned, f);
    u = (u + 0x7fff + ((u >> 16) & 1)) >> 16;   // RNE
    return (unsigned short)u;
}

// ---------------- x fp32 -> bf16 ----------------
__global__ __launch_bounds__(256) void cvt_x_kernel(const float* __restrict__ x,
                                                    unsigned short* __restrict__ xb, int n8)
{
    int i = blockIdx.x * 256 + threadIdx.x;
    if (i >= n8) return;
    float4 a = ((const float4*)x)[i * 2];
    float4 b = ((const float4*)x)[i * 2 + 1];
    short8 o;
    o[0] = f2bf(a.x); o[1] = f2bf(a.y); o[2] = f2bf(a.z); o[3] = f2bf(a.w);
    o[4] = f2bf(b.x); o[5] = f2bf(b.y); o[6] = f2bf(b.z); o[7] = f2bf(b.w);
    ((short8*)xb)[i] = o;
}

// ---------------- mask fp32 {0,0.5,1} -> u8 {0,1,2} ----------------
__global__ __launch_bounds__(256) void cvt_mask_kernel(const float* __restrict__ m,
                                                       unsigned char* __restrict__ mu, int n4)
{
    int i = blockIdx.x * 256 + threadIdx.x;
    if (i >= n4) return;
    float4 v = ((const float4*)m)[i];
    uchar4 o = { (unsigned char)(v.x * 2.0f + 0.5f),
                 (unsigned char)(v.y * 2.0f + 0.5f),
                 (unsigned char)(v.z * 2.0f + 0.5f),
                 (unsigned char)(v.w * 2.0f + 0.5f) };
    ((uchar4*)mu)[i] = o;
}

// ---------------- W [K][N] fp32 -> Wt [N][K] bf16 ----------------
__global__ __launch_bounds__(256) void cvt_wt_kernel(const float* __restrict__ W,
                                                     unsigned short* __restrict__ Wt)
{
    __shared__ float tile[64][65];
    int t = threadIdx.x;
    int c0 = blockIdx.x * 64;   // n
    int r0 = blockIdx.y * 64;   // k
    #pragma unroll
    for (int i = 0; i < 16; i++) {
        int e = i * 256 + t, r = e >> 6, c = e & 63;
        tile[c][r] = W[(size_t)(r0 + r) * D_MODEL + c0 + c];
    }
    __syncthreads();
    #pragma unroll
    for (int i = 0; i < 16; i++) {
        int e = i * 256 + t, n = e >> 6, kk = e & 63;
        Wt[(size_t)(c0 + n) * D_MODEL + r0 + kk] = f2bf(tile[n][kk]);
    }
}

// ---------------- fused QKV GEMM: [q|k|v] = x @ [Wq|Wk|Wv] + b ----------------
// Wt [1536][512] bf16 (rows: 0..511 q, 512..1023 k, 1024..1535 v)
// q: bf16 [bh][t][64] scaled by QSCALE; k: bf16 [bh][t][64]; v: bf16 [bh][64][T]
__global__ __launch_bounds__(512) void gemm_qkv_kernel(
    const unsigned short* __restrict__ A, const unsigned short* __restrict__ Wt,
    const float* __restrict__ bq, const float* __restrict__ bk, const float* __restrict__ bv,
    unsigned short* __restrict__ qb, unsigned short* __restrict__ kb,
    unsigned short* __restrict__ vb, int M, int T)
{
    constexpr int K = D_MODEL;
    __shared__ unsigned short As[2][128 * 32];
    __shared__ unsigned short Bs[2][128 * 32];
    int t = threadIdx.x;
    int lane = t & 63, w = t >> 6;
    int ql = lane & 15, kg = lane >> 4;
    int m0 = blockIdx.y * 128, n0 = blockIdx.x * 128;
    int wm = w >> 2, wn = w & 3;
    bool vmode = (n0 >= 1024);

    const unsigned short* srcA = A + (size_t)(m0 + (t >> 2)) * K + (t & 3) * 8;
    const unsigned short* srcB = Wt + (size_t)(n0 + (t >> 2)) * K + (t & 3) * 8;

    f32x4 acc[4][2];
    #pragma unroll
    for (int i = 0; i < 4; i++)
        #pragma unroll
        for (int j = 0; j < 2; j++) { f32x4 z = {0.f, 0.f, 0.f, 0.f}; acc[i][j] = z; }

    constexpr int NIT = K / 32;
    int cur = 0;
    __builtin_amdgcn_global_load_lds((as1_uint*)(srcA),
        (as3_uint*)((char*)&As[0][0] + w * 1024), 16, 0, 0);
    __builtin_amdgcn_global_load_lds((as1_uint*)(srcB),
        (as3_uint*)((char*)&Bs[0][0] + w * 1024), 16, 0, 0);
    __syncthreads();

    for (int it = 0; it < NIT; ++it) {
        if (it + 1 < NIT) {
            int k0 = (it + 1) * 32;
            __builtin_amdgcn_global_load_lds((as1_uint*)(srcA + k0),
                (as3_uint*)((char*)&As[cur ^ 1][0] + w * 1024), 16, 0, 0);
            __builtin_amdgcn_global_load_lds((as1_uint*)(srcB + k0),
                (as3_uint*)((char*)&Bs[cur ^ 1][0] + w * 1024), 16, 0, 0);
        }
        short8 af[4], bfr[2];
        #pragma unroll
        for (int fm = 0; fm < 4; fm++)
            af[fm] = *(const short8*)((const char*)&As[cur][0] + (wm * 64 + fm * 16 + ql) * 64 + kg * 16);
        #pragma unroll
        for (int fn = 0; fn < 2; fn++)
            bfr[fn] = *(const short8*)((const char*)&Bs[cur][0] + (wn * 32 + fn * 16 + ql) * 64 + kg * 16);
        if (vmode) {
            #pragma unroll
            for (int fm = 0; fm < 4; fm++)
                #pragma unroll
                for (int fn = 0; fn < 2; fn++)
                    acc[fm][fn] = __builtin_amdgcn_mfma_f32_16x16x32_bf16(bfr[fn], af[fm], acc[fm][fn], 0, 0, 0);
        } else {
            #pragma unroll
            for (int fm = 0; fm < 4; fm++)
                #pragma unroll
                for (int fn = 0; fn < 2; fn++)
                    acc[fm][fn] = __builtin_amdgcn_mfma_f32_16x16x32_bf16(af[fm], bfr[fn], acc[fm][fn], 0, 0, 0);
        }
        __syncthreads();
        cur ^= 1;
    }

    #pragma unroll
    for (int fm = 0; fm < 4; fm++) {
        #pragma unroll
        for (int fn = 0; fn < 2; fn++) {
            if (vmode) {
                int m = m0 + wm * 64 + fm * 16 + ql;
                int b = m / T, tt = m % T;
                #pragma unroll
                for (int r = 0; r < 4; r++) {
                    int n = (n0 - 1024) + wn * 32 + fn * 16 + kg * 4 + r;
                    float val = acc[fm][fn][r] + bv[n];
                    int h = n >> 6, d = n & 63;
                    vb[((size_t)(b * N_HEADS + h) * DK + d) * T + tt] = f2bf(val);
                }
            } else {
                int n = n0 + wn * 32 + fn * 16 + ql;
                int nn = n & 511;
                bool isq = (n0 < 512);
                float bn = isq ? bq[nn] : bk[nn];
                unsigned short* dst = isq ? qb : kb;
                int h = nn >> 6, d = nn & 63;
                #pragma unroll
                for (int r = 0; r < 4; r++) {
                    int m = m0 + wm * 64 + fm * 16 + kg * 4 + r;
                    int b = m / T, tt = m % T;
                    float val = acc[fm][fn][r] + bn;
                    if (isq) val *= QSCALE;
                    dst[((size_t)(b * N_HEADS + h) * T + tt) * DK + d] = f2bf(val);
                }
            }
        }
    }
}

// ---------------- out-proj GEMM: fp32 out = attb @ Wo + bo ----------------
__global__ __launch_bounds__(512) void gemm_out_kernel(
    const unsigned short* __restrict__ A, const unsigned short* __restrict__ Bt,
    const float* __restrict__ bias, float* __restrict__ outp, int M)
{
    constexpr int K = D_MODEL;
    __shared__ unsigned short As[2][128 * 32];
    __shared__ unsigned short Bs[2][128 * 32];
    int t = threadIdx.x;
    int lane = t & 63, w = t >> 6;
    int ql = lane & 15, kg = lane >> 4;
    int m0 = blockIdx.y * 128, n0 = blockIdx.x * 128;
    int wm = w >> 2, wn = w & 3;

    const unsigned short* srcA = A + (size_t)(m0 + (t >> 2)) * K + (t & 3) * 8;
    const unsigned short* srcB = Bt + (size_t)(n0 + (t >> 2)) * K + (t & 3) * 8;

    f32x4 acc[4][2];
    #pragma unroll
    for (int i = 0; i < 4; i++)
        #pragma unroll
        for (int j = 0; j < 2; j++) { f32x4 z = {0.f, 0.f, 0.f, 0.f}; acc[i][j] = z; }

    constexpr int NIT = K / 32;
    int cur = 0;
    __builtin_amdgcn_global_load_lds((as1_uint*)(srcA),
        (as3_uint*)((char*)&As[0][0] + w * 1024), 16, 0, 0);
    __builtin_amdgcn_global_load_lds((as1_uint*)(srcB),
        (as3_uint*)((char*)&Bs[0][0] + w * 1024), 16, 0, 0);
    __syncthreads();

    for (int it = 0; it < NIT; ++it) {
        if (it + 1 < NIT) {
            int k0 = (it + 1) * 32;
            __builtin_amdgcn_global_load_lds((as1_uint*)(srcA + k0),
                (as3_uint*)((char*)&As[cur ^ 1][0] + w * 1024), 16, 0, 0);
            __builtin_amdgcn_global_load_lds((as1_uint*)(srcB + k0),
                (as3_uint*)((char*)&Bs[cur ^ 1][0] + w * 1024), 16, 0, 0);
        }
        short8 af[4], bfr[2];
        #pragma unroll
        for (int fm = 0; fm < 4; fm++)
            af[fm] = *(const short8*)((const char*)&As[cur][0] + (wm * 64 + fm * 16 + ql) * 64 + kg * 16);
        #pragma unroll
        for (int fn = 0; fn < 2; fn++)
            bfr[fn] = *(const short8*)((const char*)&Bs[cur][0] + (wn * 32 + fn * 16 + ql) * 64 + kg * 16);
        #pragma unroll
        for (int fm = 0; fm < 4; fm++)
            #pragma unroll
            for (int fn = 0; fn < 2; fn++)
                acc[fm][fn] = __builtin_amdgcn_mfma_f32_16x16x32_bf16(af[fm], bfr[fn], acc[fm][fn], 0, 0, 0);
        __syncthreads();
        cur ^= 1;
    }

    #pragma unroll
    for (int fm = 0; fm < 4; fm++) {
        #pragma unroll
        for (int fn = 0; fn < 2; fn++) {
            int n = n0 + wn * 32 + fn * 16 + ql;
            float bn = bias[n];
            #pragma unroll
            for (int r = 0; r < 4; r++) {
                int m = m0 + wm * 64 + fm * 16 + kg * 4 + r;
                outp[(size_t)m * D_MODEL + n] = acc[fm][fn][r] + bn;
            }
        }
    }
}

// ---------------- MFMA flash attention v8: KVBLK=128, 1 barrier / 128 cols ----------------
// q pre-scaled by QSCALE; k [bh][T][64]; v [bh][64][T]; mu u8 [T][T]; out bf16 [M][512].
// LDS 80KB: Ks dbuf 2x16K, Vt dbuf 2x16K, Ps 16K (reused across the two 64-col halves).
__global__ __launch_bounds__(256) void attn_mfma_kernel(
    const unsigned short* __restrict__ q, const unsigned short* __restrict__ k,
    const unsigned short* __restrict__ v, const unsigned char* __restrict__ mu,
    unsigned short* __restrict__ out, int B, int T)
{
    __shared__ unsigned short Ks[2][128 * 64];
    __shared__ unsigned short Vt[2][64 * 128];
    __shared__ unsigned short Ps[4][32 * 64];

    int t = threadIdx.x;
    int lane = t & 63, w = t >> 6;
    int ql = lane & 15, kg = lane >> 4;
    int bh = blockIdx.x;
    int qt = blockIdx.y;
    int hh = bh & (N_HEADS - 1), b = bh >> 3;
    int qr0 = qt * 128;

    const char* kbase = (const char*)(k + (size_t)bh * T * DK);
    const char* vbase = (const char*)(v + (size_t)bh * DK * T);

    // staging: 4 chunks of 16B per thread for each of K and V (16KB tiles)
    // K: LDS linear lin, row=lin>>7 (128B rows); global src pre-XOR'd
    // V: rows are d (256B rows, stride 2T in global); same XOR within row
    const char* gK[4];
    const char* gV[4];
    int linv[4];
    #pragma unroll
    for (int i = 0; i < 4; i++) {
        int lin = i * 4096 + t * 16;
        linv[i] = lin;
        int krow = lin >> 7;
        gK[i] = kbase + ((lin & 127) ^ ((krow & 7) << 4)) + (size_t)krow * 128;
        int vrow = lin >> 8;
        gV[i] = vbase + (size_t)vrow * (2 * T) + ((lin & 255) ^ ((vrow & 7) << 4));
    }

    // Q fragments: 2 per wave (rows w*32 + qf*16 + ql)
    short8 qfr[2][2];
    #pragma unroll
    for (int qf = 0; qf < 2; qf++) {
        const unsigned short* qrow = q + ((size_t)bh * T + qr0 + w * 32 + qf * 16 + ql) * DK + kg * 8;
        qfr[qf][0] = *(const short8*)(qrow);
        qfr[qf][1] = *(const short8*)(qrow + 32);
    }

    const unsigned char* mrow0 = mu + (size_t)(qr0 + w * 32 + ql) * T + kg * 4;
    const unsigned char* mrow1 = mrow0 + (size_t)16 * T;

    f32x4 oacc[2][4];
    #pragma unroll
    for (int qf = 0; qf < 2; qf++)
        #pragma unroll
        for (int c = 0; c < 4; c++) { f32x4 z = {0.f, 0.f, 0.f, 0.f}; oacc[qf][c] = z; }
    float lacc0 = 0.f, lacc1 = 0.f;

    // prologue: mask tile 0 (8 dwords per frag) + stage K/V tile 0 -> buf 0
    unsigned mcur0[8], mcur1[8];
    #pragma unroll
    for (int c = 0; c < 8; c++) {
        mcur0[c] = *(const unsigned*)(mrow0 + c * 16);
        mcur1[c] = *(const unsigned*)(mrow1 + c * 16);
    }
    #pragma unroll
    for (int i = 0; i < 4; i++) {
        __builtin_amdgcn_global_load_lds((as1_uint*)gK[i],
            (as3_uint*)((char*)&Ks[0][0] + linv[i]), 16, 0, 0);
        __builtin_amdgcn_global_load_lds((as1_uint*)gV[i],
            (as3_uint*)((char*)&Vt[0][0] + linv[i]), 16, 0, 0);
    }

    int ntiles = T / 128;
    for (int kt = 0; kt < ntiles; kt++) {
        __syncthreads();   // buf[cur] staged (vmcnt drained); prev tile reads done
        int cur = kt & 1;
        bool havenext = (kt + 1) < ntiles;

        unsigned mnxt0[8], mnxt1[8];
        if (havenext) {
            const unsigned char* mp0 = mrow0 + (size_t)(kt + 1) * 128;
            const unsigned char* mp1 = mrow1 + (size_t)(kt + 1) * 128;
            #pragma unroll
            for (int c = 0; c < 8; c++) {
                mnxt0[c] = *(const unsigned*)(mp0 + c * 16);
                mnxt1[c] = *(const unsigned*)(mp1 + c * 16);
            }
            size_t ko = (size_t)(kt + 1) * 16384;   // 128 rows * 128B
            size_t vo = (size_t)(kt + 1) * 256;     // 128 cols * 2B
            #pragma unroll
            for (int i = 0; i < 4; i++) {
                __builtin_amdgcn_global_load_lds((as1_uint*)(gK[i] + ko),
                    (as3_uint*)((char*)&Ks[cur ^ 1][0] + linv[i]), 16, 0, 0);
                __builtin_amdgcn_global_load_lds((as1_uint*)(gV[i] + vo),
                    (as3_uint*)((char*)&Vt[cur ^ 1][0] + linv[i]), 16, 0, 0);
            }
        }

        // two 64-col halves; Ps reused (same-wave LDS ordering)
        #pragma unroll
        for (int h = 0; h < 2; h++) {
            // QK^T (swapped): lane -> q-row ql, kcols h*64 + c*16 + kg*4 + r
            f32x4 sacc[2][4];
            #pragma unroll
            for (int qf = 0; qf < 2; qf++)
                #pragma unroll
                for (int c = 0; c < 4; c++) { f32x4 z = {0.f, 0.f, 0.f, 0.f}; sacc[qf][c] = z; }
            __builtin_amdgcn_s_setprio(1);
            #pragma unroll
            for (int ks = 0; ks < 2; ks++) {
                #pragma unroll
                for (int c = 0; c < 4; c++) {
                    int row = h * 64 + c * 16 + ql;
                    short8 kf = *(const short8*)((const char*)&Ks[cur][0] +
                                ((row * 128 + ks * 64 + kg * 16) ^ ((row & 7) << 4)));
                    sacc[0][c] = __builtin_amdgcn_mfma_f32_16x16x32_bf16(kf, qfr[0][ks], sacc[0][c], 0, 0, 0);
                    sacc[1][c] = __builtin_amdgcn_mfma_f32_16x16x32_bf16(kf, qfr[1][ks], sacc[1][c], 0, 0, 0);
                }
            }
            __builtin_amdgcn_s_setprio(0);

            // softmax: p = exp2(s * m), m in {0,1,2}
            #pragma unroll
            for (int c = 0; c < 4; c++) {
                unsigned mw = mcur0[h * 4 + c];
                float p0 = __builtin_amdgcn_exp2f(sacc[0][c][0] * (float)(mw & 0xffu));
                float p1 = __builtin_amdgcn_exp2f(sacc[0][c][1] * (float)((mw >> 8) & 0xffu));
                float p2 = __builtin_amdgcn_exp2f(sacc[0][c][2] * (float)((mw >> 16) & 0xffu));
                float p3 = __builtin_amdgcn_exp2f(sacc[0][c][3] * (float)(mw >> 24));
                lacc0 += (p0 + p1) + (p2 + p3);
                unsigned lo, hi;
                asm("v_cvt_pk_bf16_f32 %0, %1, %2" : "=v"(lo) : "v"(p0), "v"(p1));
                asm("v_cvt_pk_bf16_f32 %0, %1, %2" : "=v"(hi) : "v"(p2), "v"(p3));
                int byteoff = (ql * 128 + (c * 16 + kg * 4) * 2) ^ ((ql & 7) << 4);
                uint2 pr = { lo, hi };
                *(uint2*)((char*)&Ps[w][0] + byteoff) = pr;

                unsigned nw = mcur1[h * 4 + c];
                float q0 = __builtin_amdgcn_exp2f(sacc[1][c][0] * (float)(nw & 0xffu));
                float q1 = __builtin_amdgcn_exp2f(sacc[1][c][1] * (float)((nw >> 8) & 0xffu));
                float q2 = __builtin_amdgcn_exp2f(sacc[1][c][2] * (float)((nw >> 16) & 0xffu));
                float q3 = __builtin_amdgcn_exp2f(sacc[1][c][3] * (float)(nw >> 24));
                lacc1 += (q0 + q1) + (q2 + q3);
                unsigned lo1, hi1;
                asm("v_cvt_pk_bf16_f32 %0, %1, %2" : "=v"(lo1) : "v"(q0), "v"(q1));
                asm("v_cvt_pk_bf16_f32 %0, %1, %2" : "=v"(hi1) : "v"(q2), "v"(q3));
                uint2 pr1 = { lo1, hi1 };
                *(uint2*)((char*)&Ps[w][0] + 2048 + byteoff) = pr1;
            }

            // PV: V^T rows are d (256B LDS rows), cols h*128.. within tile
            __builtin_amdgcn_s_setprio(1);
            #pragma unroll
            for (int ks = 0; ks < 2; ks++) {
                int pboff = (ql * 128 + ks * 64 + kg * 16) ^ ((ql & 7) << 4);
                short8 pa0 = *(const short8*)((const char*)&Ps[w][0] + pboff);
                short8 pa1 = *(const short8*)((const char*)&Ps[w][0] + 2048 + pboff);
                #pragma unroll
                for (int c2 = 0; c2 < 4; c2++) {
                    int rowd = c2 * 16 + ql;
                    short8 vb = *(const short8*)((const char*)&Vt[cur][0] +
                                ((rowd * 256 + h * 128 + ks * 64 + kg * 16) ^ ((rowd & 7) << 4)));
                    oacc[0][c2] = __builtin_amdgcn_mfma_f32_16x16x32_bf16(pa0, vb, oacc[0][c2], 0, 0, 0);
                    oacc[1][c2] = __builtin_amdgcn_mfma_f32_16x16x32_bf16(pa1, vb, oacc[1][c2], 0, 0, 0);
                }
            }
            __builtin_amdgcn_s_setprio(0);
        }

        if (havenext) {
            #pragma unroll
            for (int c = 0; c < 8; c++) { mcur0[c] = mnxt0[c]; mcur1[c] = mnxt1[c]; }
        }
    }

    // deferred l-reduction + store
    lacc0 += __shfl_xor(lacc0, 16, 64);
    lacc0 += __shfl_xor(lacc0, 32, 64);
    lacc1 += __shfl_xor(lacc1, 16, 64);
    lacc1 += __shfl_xor(lacc1, 32, 64);
    #pragma unroll
    for (int qf = 0; qf < 2; qf++) {
        float la = qf ? lacc1 : lacc0;
        #pragma unroll
        for (int r = 0; r < 4; r++) {
            float linvv = 1.0f / __shfl(la, kg * 4 + r, 64);
            size_t rowo = ((size_t)b * T + qr0 + w * 32 + qf * 16 + kg * 4 + r) * D_MODEL + hh * DK;
            #pragma unroll
            for (int c2 = 0; c2 < 4; c2++)
                out[rowo + c2 * 16 + ql] = f2bf(oacc[qf][c2][r] * linvv);
        }
    }
}

extern "C" void kernel_launch(void* const* d_in, const int* in_sizes, int n_in,
                              void* d_out, int out_size, void* d_ws, size_t ws_size,
                              hipStream_t stream) {
    const float* x    = (const float*)d_in[0];
    const float* mask = (const float*)d_in[1];
    const float* Wq   = (const float*)d_in[2];
    const float* bq   = (const float*)d_in[3];
    const float* Wk   = (const float*)d_in[4];
    const float* bk   = (const float*)d_in[5];
    const float* Wv   = (const float*)d_in[6];
    const float* bv   = (const float*)d_in[7];
    const float* Wo   = (const float*)d_in[8];
    const float* bo   = (const float*)d_in[9];

    int T = (int)(sqrt((double)in_sizes[1]) + 0.5);   // 4096
    int C = D_MODEL;
    int B = in_sizes[0] / (T * C);                    // 2
    int M = B * T;

    size_t MK = (size_t)M * C;
    unsigned short* xb  = (unsigned short*)d_ws;
    unsigned short* Wtq = xb + MK;                    // [1536][512] contiguous
    unsigned short* Wtk = Wtq + (size_t)C * C;
    unsigned short* Wtv = Wtk + (size_t)C * C;
    unsigned short* Wto = Wtv + (size_t)C * C;
    unsigned short* qb  = Wto + (size_t)C * C;
    unsigned short* kb  = qb + MK;
    unsigned short* vb  = kb + MK;
    unsigned short* attb = vb + MK;
    unsigned char*  mu  = (unsigned char*)(attb + MK);

    int n8 = (int)(MK / 8);
    cvt_x_kernel<<<(n8 + 255) / 256, 256, 0, stream>>>(x, xb, n8);
    int n4 = T * T / 4;
    cvt_mask_kernel<<<(n4 + 255) / 256, 256, 0, stream>>>(mask, mu, n4);
    dim3 wtg(C / 64, C / 64, 1);
    cvt_wt_kernel<<<wtg, 256, 0, stream>>>(Wq, Wtq);
    cvt_wt_kernel<<<wtg, 256, 0, stream>>>(Wk, Wtk);
    cvt_wt_kernel<<<wtg, 256, 0, stream>>>(Wv, Wtv);
    cvt_wt_kernel<<<wtg, 256, 0, stream>>>(Wo, Wto);

    dim3 gq(3 * C / 128, M / 128, 1);
    gemm_qkv_kernel<<<gq, 512, 0, stream>>>(xb, Wtq, bq, bk, bv, qb, kb, vb, M, T);

    dim3 ga(B * N_HEADS, T / 128, 1);
    attn_mfma_kernel<<<ga, 256, 0, stream>>>(qb, kb, vb, mu, attb, B, T);

    dim3 gg(C / 128, M / 128, 1);
    gemm_out_kernel<<<gg, 512, 0, stream>>>(attb, Wto, bo, (float*)d_out, M);
}

// Round 9
// 220.913 us; speedup vs baseline: 1.5287x; 1.5287x over previous
//
#include <hip/hip_runtime.h>
#include <math.h>

#define D_MODEL 512
#define N_HEADS 8
#define DK 64
#define QSCALE (0.0625f * 1.44269504089f)

typedef __attribute__((ext_vector_type(8))) short short8;
typedef __attribute__((ext_vector_type(4))) float f32x4;
typedef __attribute__((ext_vector_type(16))) float f32x16;

typedef __attribute__((address_space(1))) const unsigned as1_uint;
typedef __attribute__((address_space(3))) unsigned as3_uint;

__device__ __forceinline__ unsigned short f2bf(float f) {
    unsigned u = __builtin_bit_cast(unsigned, f);
    u = (u + 0x7fff + ((u >> 16) & 1)) >> 16;   // RNE
    return (unsigned short)u;
}

// ---------------- x fp32 -> bf16 ----------------
__global__ __launch_bounds__(256) void cvt_x_kernel(const float* __restrict__ x,
                                                    unsigned short* __restrict__ xb, int n8)
{
    int i = blockIdx.x * 256 + threadIdx.x;
    if (i >= n8) return;
    float4 a = ((const float4*)x)[i * 2];
    float4 b = ((const float4*)x)[i * 2 + 1];
    short8 o;
    o[0] = f2bf(a.x); o[1] = f2bf(a.y); o[2] = f2bf(a.z); o[3] = f2bf(a.w);
    o[4] = f2bf(b.x); o[5] = f2bf(b.y); o[6] = f2bf(b.z); o[7] = f2bf(b.w);
    ((short8*)xb)[i] = o;
}

// ---------------- mask fp32 {0,0.5,1} -> u8 {0,1,2} ----------------
__global__ __launch_bounds__(256) void cvt_mask_kernel(const float* __restrict__ m,
                                                       unsigned char* __restrict__ mu, int n4)
{
    int i = blockIdx.x * 256 + threadIdx.x;
    if (i >= n4) return;
    float4 v = ((const float4*)m)[i];
    uchar4 o = { (unsigned char)(v.x * 2.0f + 0.5f),
                 (unsigned char)(v.y * 2.0f + 0.5f),
                 (unsigned char)(v.z * 2.0f + 0.5f),
                 (unsigned char)(v.w * 2.0f + 0.5f) };
    ((uchar4*)mu)[i] = o;
}

// ---------------- W [K][N] fp32 -> Wt [N][K] bf16 ----------------
__global__ __launch_bounds__(256) void cvt_wt_kernel(const float* __restrict__ W,
                                                     unsigned short* __restrict__ Wt)
{
    __shared__ float tile[64][65];
    int t = threadIdx.x;
    int c0 = blockIdx.x * 64;   // n
    int r0 = blockIdx.y * 64;   // k
    #pragma unroll
    for (int i = 0; i < 16; i++) {
        int e = i * 256 + t, r = e >> 6, c = e & 63;
        tile[c][r] = W[(size_t)(r0 + r) * D_MODEL + c0 + c];
    }
    __syncthreads();
    #pragma unroll
    for (int i = 0; i < 16; i++) {
        int e = i * 256 + t, n = e >> 6, kk = e & 63;
        Wt[(size_t)(c0 + n) * D_MODEL + r0 + kk] = f2bf(tile[n][kk]);
    }
}

// ---------------- fused QKV GEMM: [q|k|v] = x @ [Wq|Wk|Wv] + b ----------------
__global__ __launch_bounds__(512) void gemm_qkv_kernel(
    const unsigned short* __restrict__ A, const unsigned short* __restrict__ Wt,
    const float* __restrict__ bq, const float* __restrict__ bk, const float* __restrict__ bv,
    unsigned short* __restrict__ qb, unsigned short* __restrict__ kb,
    unsigned short* __restrict__ vb, int M, int T)
{
    constexpr int K = D_MODEL;
    __shared__ unsigned short As[2][128 * 32];
    __shared__ unsigned short Bs[2][128 * 32];
    int t = threadIdx.x;
    int lane = t & 63, w = t >> 6;
    int ql = lane & 15, kg = lane >> 4;
    int m0 = blockIdx.y * 128, n0 = blockIdx.x * 128;
    int wm = w >> 2, wn = w & 3;
    bool vmode = (n0 >= 1024);

    const unsigned short* srcA = A + (size_t)(m0 + (t >> 2)) * K + (t & 3) * 8;
    const unsigned short* srcB = Wt + (size_t)(n0 + (t >> 2)) * K + (t & 3) * 8;

    f32x4 acc[4][2];
    #pragma unroll
    for (int i = 0; i < 4; i++)
        #pragma unroll
        for (int j = 0; j < 2; j++) { f32x4 z = {0.f, 0.f, 0.f, 0.f}; acc[i][j] = z; }

    constexpr int NIT = K / 32;
    int cur = 0;
    __builtin_amdgcn_global_load_lds((as1_uint*)(srcA),
        (as3_uint*)((char*)&As[0][0] + w * 1024), 16, 0, 0);
    __builtin_amdgcn_global_load_lds((as1_uint*)(srcB),
        (as3_uint*)((char*)&Bs[0][0] + w * 1024), 16, 0, 0);
    __syncthreads();

    for (int it = 0; it < NIT; ++it) {
        if (it + 1 < NIT) {
            int k0 = (it + 1) * 32;
            __builtin_amdgcn_global_load_lds((as1_uint*)(srcA + k0),
                (as3_uint*)((char*)&As[cur ^ 1][0] + w * 1024), 16, 0, 0);
            __builtin_amdgcn_global_load_lds((as1_uint*)(srcB + k0),
                (as3_uint*)((char*)&Bs[cur ^ 1][0] + w * 1024), 16, 0, 0);
        }
        short8 af[4], bfr[2];
        #pragma unroll
        for (int fm = 0; fm < 4; fm++)
            af[fm] = *(const short8*)((const char*)&As[cur][0] + (wm * 64 + fm * 16 + ql) * 64 + kg * 16);
        #pragma unroll
        for (int fn = 0; fn < 2; fn++)
            bfr[fn] = *(const short8*)((const char*)&Bs[cur][0] + (wn * 32 + fn * 16 + ql) * 64 + kg * 16);
        if (vmode) {
            #pragma unroll
            for (int fm = 0; fm < 4; fm++)
                #pragma unroll
                for (int fn = 0; fn < 2; fn++)
                    acc[fm][fn] = __builtin_amdgcn_mfma_f32_16x16x32_bf16(bfr[fn], af[fm], acc[fm][fn], 0, 0, 0);
        } else {
            #pragma unroll
            for (int fm = 0; fm < 4; fm++)
                #pragma unroll
                for (int fn = 0; fn < 2; fn++)
                    acc[fm][fn] = __builtin_amdgcn_mfma_f32_16x16x32_bf16(af[fm], bfr[fn], acc[fm][fn], 0, 0, 0);
        }
        __syncthreads();
        cur ^= 1;
    }

    #pragma unroll
    for (int fm = 0; fm < 4; fm++) {
        #pragma unroll
        for (int fn = 0; fn < 2; fn++) {
            if (vmode) {
                int m = m0 + wm * 64 + fm * 16 + ql;
                int b = m / T, tt = m % T;
                #pragma unroll
                for (int r = 0; r < 4; r++) {
                    int n = (n0 - 1024) + wn * 32 + fn * 16 + kg * 4 + r;
                    float val = acc[fm][fn][r] + bv[n];
                    int h = n >> 6, d = n & 63;
                    vb[((size_t)(b * N_HEADS + h) * DK + d) * T + tt] = f2bf(val);
                }
            } else {
                int n = n0 + wn * 32 + fn * 16 + ql;
                int nn = n & 511;
                bool isq = (n0 < 512);
                float bn = isq ? bq[nn] : bk[nn];
                unsigned short* dst = isq ? qb : kb;
                int h = nn >> 6, d = nn & 63;
                #pragma unroll
                for (int r = 0; r < 4; r++) {
                    int m = m0 + wm * 64 + fm * 16 + kg * 4 + r;
                    int b = m / T, tt = m % T;
                    float val = acc[fm][fn][r] + bn;
                    if (isq) val *= QSCALE;
                    dst[((size_t)(b * N_HEADS + h) * T + tt) * DK + d] = f2bf(val);
                }
            }
        }
    }
}

// ---------------- out-proj GEMM: fp32 out = attb @ Wo + bo ----------------
__global__ __launch_bounds__(512) void gemm_out_kernel(
    const unsigned short* __restrict__ A, const unsigned short* __restrict__ Bt,
    const float* __restrict__ bias, float* __restrict__ outp, int M)
{
    constexpr int K = D_MODEL;
    __shared__ unsigned short As[2][128 * 32];
    __shared__ unsigned short Bs[2][128 * 32];
    int t = threadIdx.x;
    int lane = t & 63, w = t >> 6;
    int ql = lane & 15, kg = lane >> 4;
    int m0 = blockIdx.y * 128, n0 = blockIdx.x * 128;
    int wm = w >> 2, wn = w & 3;

    const unsigned short* srcA = A + (size_t)(m0 + (t >> 2)) * K + (t & 3) * 8;
    const unsigned short* srcB = Bt + (size_t)(n0 + (t >> 2)) * K + (t & 3) * 8;

    f32x4 acc[4][2];
    #pragma unroll
    for (int i = 0; i < 4; i++)
        #pragma unroll
        for (int j = 0; j < 2; j++) { f32x4 z = {0.f, 0.f, 0.f, 0.f}; acc[i][j] = z; }

    constexpr int NIT = K / 32;
    int cur = 0;
    __builtin_amdgcn_global_load_lds((as1_uint*)(srcA),
        (as3_uint*)((char*)&As[0][0] + w * 1024), 16, 0, 0);
    __builtin_amdgcn_global_load_lds((as1_uint*)(srcB),
        (as3_uint*)((char*)&Bs[0][0] + w * 1024), 16, 0, 0);
    __syncthreads();

    for (int it = 0; it < NIT; ++it) {
        if (it + 1 < NIT) {
            int k0 = (it + 1) * 32;
            __builtin_amdgcn_global_load_lds((as1_uint*)(srcA + k0),
                (as3_uint*)((char*)&As[cur ^ 1][0] + w * 1024), 16, 0, 0);
            __builtin_amdgcn_global_load_lds((as1_uint*)(srcB + k0),
                (as3_uint*)((char*)&Bs[cur ^ 1][0] + w * 1024), 16, 0, 0);
        }
        short8 af[4], bfr[2];
        #pragma unroll
        for (int fm = 0; fm < 4; fm++)
            af[fm] = *(const short8*)((const char*)&As[cur][0] + (wm * 64 + fm * 16 + ql) * 64 + kg * 16);
        #pragma unroll
        for (int fn = 0; fn < 2; fn++)
            bfr[fn] = *(const short8*)((const char*)&Bs[cur][0] + (wn * 32 + fn * 16 + ql) * 64 + kg * 16);
        #pragma unroll
        for (int fm = 0; fm < 4; fm++)
            #pragma unroll
            for (int fn = 0; fn < 2; fn++)
                acc[fm][fn] = __builtin_amdgcn_mfma_f32_16x16x32_bf16(af[fm], bfr[fn], acc[fm][fn], 0, 0, 0);
        __syncthreads();
        cur ^= 1;
    }

    #pragma unroll
    for (int fm = 0; fm < 4; fm++) {
        #pragma unroll
        for (int fn = 0; fn < 2; fn++) {
            int n = n0 + wn * 32 + fn * 16 + ql;
            float bn = bias[n];
            #pragma unroll
            for (int r = 0; r < 4; r++) {
                int m = m0 + wm * 64 + fm * 16 + kg * 4 + r;
                outp[(size_t)m * D_MODEL + n] = acc[fm][fn][r] + bn;
            }
        }
    }
}

// ---------------- MFMA flash attention v9: 32x32x16, in-register P ----------------
// q pre-scaled by QSCALE; k [bh][T][64]; v [bh][64][T]; mu u8 [T][T]; out bf16 [M][512].
// R6 schedule (KVBLK=64, dbuf K/V, gload_lds staging), inner math on 32x32 MFMA:
// swapped QK^T -> lane owns q=lane&31; P rebuilt in-register via cvt_pk+permlane32_swap.
__global__ __launch_bounds__(256) void attn_mfma_kernel(
    const unsigned short* __restrict__ q, const unsigned short* __restrict__ k,
    const unsigned short* __restrict__ v, const unsigned char* __restrict__ mu,
    unsigned short* __restrict__ out, int B, int T)
{
    __shared__ unsigned short Ks[2][64 * 64];
    __shared__ unsigned short Vt[2][64 * 64];

    int t = threadIdx.x;
    int lane = t & 63, w = t >> 6;
    int ln = lane & 31, hi = lane >> 5;
    int bh = blockIdx.x;
    int qt = blockIdx.y;
    int hh = bh & (N_HEADS - 1), b = bh >> 3;
    int qr0 = qt * 128;

    const char* kbase = (const char*)(k + (size_t)bh * T * DK);
    const char* vbase = (const char*)(v + (size_t)bh * DK * T);

    // staging addresses: LDS linear dest, inverse-swizzled global source (R6)
    int lin0 = w * 1024 + lane * 16;
    int lin1 = 4096 + lin0;
    int row0 = lin0 >> 7, row1 = lin1 >> 7;
    int sw0 = (row0 & 7) << 4, sw1 = (row1 & 7) << 4;
    const char* gK0 = kbase + (lin0 ^ sw0);
    const char* gK1 = kbase + (lin1 ^ sw1);
    const char* gV0 = vbase + (size_t)row0 * (2 * T) + ((lin0 & 127) ^ sw0);
    const char* gV1 = vbase + (size_t)row1 * (2 * T) + ((lin1 & 127) ^ sw1);

    // Q B-fragments: lane holds Q[q = qr0 + w*32 + ln][ks*16 + hi*8 .. +7]
    short8 qfr[4];
    {
        const unsigned short* qrow = q + ((size_t)bh * T + qr0 + w * 32 + ln) * DK + hi * 8;
        #pragma unroll
        for (int ks = 0; ks < 4; ks++)
            qfr[ks] = *(const short8*)(qrow + ks * 16);
    }

    // mask: lane's q-row, strided dwords (kcol = rb*32 + g*8 + 4*hi + 0..3)
    const unsigned char* mbase = mu + (size_t)(qr0 + w * 32 + ln) * T + 4 * hi;

    f32x16 oacc[2];
    #pragma unroll
    for (int db = 0; db < 2; db++)
        #pragma unroll
        for (int i = 0; i < 16; i++) oacc[db][i] = 0.f;
    float lacc = 0.f;

    // prologue: mask tile 0 + stage K/V tile 0 -> buf 0
    unsigned mcur[8];
    #pragma unroll
    for (int rb = 0; rb < 2; rb++)
        #pragma unroll
        for (int g = 0; g < 4; g++)
            mcur[rb * 4 + g] = *(const unsigned*)(mbase + rb * 32 + g * 8);
    __builtin_amdgcn_global_load_lds((as1_uint*)gK0, (as3_uint*)((char*)&Ks[0][0] + lin0), 16, 0, 0);
    __builtin_amdgcn_global_load_lds((as1_uint*)gK1, (as3_uint*)((char*)&Ks[0][0] + lin1), 16, 0, 0);
    __builtin_amdgcn_global_load_lds((as1_uint*)gV0, (as3_uint*)((char*)&Vt[0][0] + lin0), 16, 0, 0);
    __builtin_amdgcn_global_load_lds((as1_uint*)gV1, (as3_uint*)((char*)&Vt[0][0] + lin1), 16, 0, 0);

    int ntiles = T / 64;
    for (int kt = 0; kt < ntiles; kt++) {
        __syncthreads();   // buf[cur] staged (vmcnt drained); prev reads done
        int cur = kt & 1;
        bool havenext = (kt + 1) < ntiles;

        unsigned mnxt[8];
        if (havenext) {
            const unsigned char* mp = mbase + (size_t)(kt + 1) * 64;
            #pragma unroll
            for (int rb = 0; rb < 2; rb++)
                #pragma unroll
                for (int g = 0; g < 4; g++)
                    mnxt[rb * 4 + g] = *(const unsigned*)(mp + rb * 32 + g * 8);
            size_t ko = (size_t)(kt + 1) * 8192;
            size_t vo = (size_t)(kt + 1) * 128;
            __builtin_amdgcn_global_load_lds((as1_uint*)(gK0 + ko),
                (as3_uint*)((char*)&Ks[cur ^ 1][0] + lin0), 16, 0, 0);
            __builtin_amdgcn_global_load_lds((as1_uint*)(gK1 + ko),
                (as3_uint*)((char*)&Ks[cur ^ 1][0] + lin1), 16, 0, 0);
            __builtin_amdgcn_global_load_lds((as1_uint*)(gV0 + vo),
                (as3_uint*)((char*)&Vt[cur ^ 1][0] + lin0), 16, 0, 0);
            __builtin_amdgcn_global_load_lds((as1_uint*)(gV1 + vo),
                (as3_uint*)((char*)&Vt[cur ^ 1][0] + lin1), 16, 0, 0);
        }

        // QK^T (swapped): sacc[rb][reg] = S[kcol = rb*32 + (reg&3)+8*(reg>>2)+4*hi][q = ln]
        f32x16 sacc[2];
        #pragma unroll
        for (int rb = 0; rb < 2; rb++)
            #pragma unroll
            for (int i = 0; i < 16; i++) sacc[rb][i] = 0.f;
        __builtin_amdgcn_s_setprio(1);
        #pragma unroll
        for (int ks = 0; ks < 4; ks++) {
            #pragma unroll
            for (int rb = 0; rb < 2; rb++) {
                int row = rb * 32 + ln;
                short8 kf = *(const short8*)((const char*)&Ks[cur][0] +
                            ((row * 128 + ks * 32 + hi * 16) ^ ((row & 7) << 4)));
                sacc[rb] = __builtin_amdgcn_mfma_f32_32x32x16_bf16(kf, qfr[ks], sacc[rb], 0, 0, 0);
            }
        }
        __builtin_amdgcn_s_setprio(0);

        // softmax: p = exp2(s*m); build PV A-frags in-register (cvt_pk + permlane32_swap)
        short8 pa[4];
        #pragma unroll
        for (int rb = 0; rb < 2; rb++) {
            float p[16];
            #pragma unroll
            for (int g = 0; g < 4; g++) {
                unsigned mw = mcur[rb * 4 + g];
                float p0 = __builtin_amdgcn_exp2f(sacc[rb][g * 4 + 0] * (float)(mw & 0xffu));
                float p1 = __builtin_amdgcn_exp2f(sacc[rb][g * 4 + 1] * (float)((mw >> 8) & 0xffu));
                float p2 = __builtin_amdgcn_exp2f(sacc[rb][g * 4 + 2] * (float)((mw >> 16) & 0xffu));
                float p3 = __builtin_amdgcn_exp2f(sacc[rb][g * 4 + 3] * (float)(mw >> 24));
                p[g * 4 + 0] = p0; p[g * 4 + 1] = p1; p[g * 4 + 2] = p2; p[g * 4 + 3] = p3;
                lacc += (p0 + p1) + (p2 + p3);
            }
            #pragma unroll
            for (int kl = 0; kl < 2; kl++) {
                int b0 = kl * 8;
                unsigned d0, d1, d2, d3;
                asm("v_cvt_pk_bf16_f32 %0, %1, %2" : "=v"(d0) : "v"(p[b0 + 0]), "v"(p[b0 + 1]));
                asm("v_cvt_pk_bf16_f32 %0, %1, %2" : "=v"(d1) : "v"(p[b0 + 2]), "v"(p[b0 + 3]));
                asm("v_cvt_pk_bf16_f32 %0, %1, %2" : "=v"(d2) : "v"(p[b0 + 4]), "v"(p[b0 + 5]));
                asm("v_cvt_pk_bf16_f32 %0, %1, %2" : "=v"(d3) : "v"(p[b0 + 6]), "v"(p[b0 + 7]));
                asm("v_permlane32_swap_b32 %0, %1" : "+v"(d0), "+v"(d2));
                asm("v_permlane32_swap_b32 %0, %1" : "+v"(d1), "+v"(d3));
                uint4 fr = { d0, d1, d2, d3 };
                pa[rb * 2 + kl] = __builtin_bit_cast(short8, fr);
            }
        }

        // PV: oacc[db] += P(32q x 64k) @ V(64k x [db*32..+31])
        __builtin_amdgcn_s_setprio(1);
        #pragma unroll
        for (int ks = 0; ks < 4; ks++) {
            #pragma unroll
            for (int db = 0; db < 2; db++) {
                int row = db * 32 + ln;
                short8 vb = *(const short8*)((const char*)&Vt[cur][0] +
                            ((row * 128 + ks * 32 + hi * 16) ^ ((row & 7) << 4)));
                oacc[db] = __builtin_amdgcn_mfma_f32_32x32x16_bf16(pa[ks], vb, oacc[db], 0, 0, 0);
            }
        }
        __builtin_amdgcn_s_setprio(0);

        if (havenext) {
            #pragma unroll
            for (int c = 0; c < 8; c++) mcur[c] = mnxt[c];
        }
    }

    // l: lane owns q=ln; other half of kcols sits at lane^32
    lacc += __shfl_xor(lacc, 32, 64);

    // store: oacc[db][reg] is O[q = (reg&3)+8*(reg>>2)+4*hi][d = db*32 + ln]
    #pragma unroll
    for (int reg = 0; reg < 16; reg++) {
        int qoff = (reg & 3) + 8 * (reg >> 2) + 4 * hi;
        float linv = 1.0f / __shfl(lacc, qoff, 64);
        size_t rowo = ((size_t)b * T + qr0 + w * 32 + qoff) * D_MODEL + hh * DK + ln;
        out[rowo]      = f2bf(oacc[0][reg] * linv);
        out[rowo + 32] = f2bf(oacc[1][reg] * linv);
    }
}

extern "C" void kernel_launch(void* const* d_in, const int* in_sizes, int n_in,
                              void* d_out, int out_size, void* d_ws, size_t ws_size,
                              hipStream_t stream) {
    const float* x    = (const float*)d_in[0];
    const float* mask = (const float*)d_in[1];
    const float* Wq   = (const float*)d_in[2];
    const float* bq   = (const float*)d_in[3];
    const float* Wk   = (const float*)d_in[4];
    const float* bk   = (const float*)d_in[5];
    const float* Wv   = (const float*)d_in[6];
    const float* bv   = (const float*)d_in[7];
    const float* Wo   = (const float*)d_in[8];
    const float* bo   = (const float*)d_in[9];

    int T = (int)(sqrt((double)in_sizes[1]) + 0.5);   // 4096
    int C = D_MODEL;
    int B = in_sizes[0] / (T * C);                    // 2
    int M = B * T;

    size_t MK = (size_t)M * C;
    unsigned short* xb  = (unsigned short*)d_ws;
    unsigned short* Wtq = xb + MK;                    // [1536][512] contiguous
    unsigned short* Wtk = Wtq + (size_t)C * C;
    unsigned short* Wtv = Wtk + (size_t)C * C;
    unsigned short* Wto = Wtv + (size_t)C * C;
    unsigned short* qb  = Wto + (size_t)C * C;
    unsigned short* kb  = qb + MK;
    unsigned short* vb  = kb + MK;
    unsigned short* attb = vb + MK;
    unsigned char*  mu  = (unsigned char*)(attb + MK);

    int n8 = (int)(MK / 8);
    cvt_x_kernel<<<(n8 + 255) / 256, 256, 0, stream>>>(x, xb, n8);
    int n4 = T * T / 4;
    cvt_mask_kernel<<<(n4 + 255) / 256, 256, 0, stream>>>(mask, mu, n4);
    dim3 wtg(C / 64, C / 64, 1);
    cvt_wt_kernel<<<wtg, 256, 0, stream>>>(Wq, Wtq);
    cvt_wt_kernel<<<wtg, 256, 0, stream>>>(Wk, Wtk);
    cvt_wt_kernel<<<wtg, 256, 0, stream>>>(Wv, Wtv);
    cvt_wt_kernel<<<wtg, 256, 0, stream>>>(Wo, Wto);

    dim3 gq(3 * C / 128, M / 128, 1);
    gemm_qkv_kernel<<<gq, 512, 0, stream>>>(xb, Wtq, bq, bk, bv, qb, kb, vb, M, T);

    dim3 ga(B * N_HEADS, T / 128, 1);
    attn_mfma_kernel<<<ga, 256, 0, stream>>>(qb, kb, vb, mu, attb, B, T);

    dim3 gg(C / 128, M / 128, 1);
    gemm_out_kernel<<<gg, 512, 0, stream>>>(attb, Wto, bo, (float*)d_out, M);
}